// Round 1
// baseline (31099.478 us; speedup 1.0000x reference)
//
#include <hip/hip_runtime.h>
#include <math.h>

// Problem dims
#define Bq   128
#define Pp   196
#define ENCC 2048
#define Dd   1024
#define Aa   1024
#define Vv   32000
#define TMx  21
#define CAPq 22

// ---- output layout (floats, concatenated in reference return order) ----
#define O_PRED 0
#define O_CAPS (Bq * TMx * Vv)          // 86016000
#define O_DECL (O_CAPS + Bq * CAPq)
#define O_SORT (O_DECL + Bq)
#define O_RELP (O_SORT + Bq)
#define O_PPOS (O_RELP + Bq * TMx)

// ---- workspace layout (float units) ----
#define WS_SORT 0                        // int[128]
#define WS_DECL 128                      // int[128]
#define WS_CAPS 256                      // int[128*22]
#define WS_H1   3072
#define WS_C1   (WS_H1 + Bq * Dd)
#define WS_H2   (WS_C1 + Bq * Dd)
#define WS_C2   (WS_H2 + Bq * Dd)
#define WS_MEAN (WS_C2 + Bq * Dd)        // 128*2048
#define WS_ATT2 (WS_MEAN + Bq * ENCC)    // 128*1024
#define WS_X1   (WS_ATT2 + Bq * Aa)      // 128*4096
#define WS_X2   (WS_X1 + Bq * 4096)      // 128*3072
#define WS_G    (WS_X2 + Bq * 3072)      // 128*4096
#define WS_AWE  (WS_G + Bq * 4096)       // 128*2048
#define WS_ATT1 (WS_AWE + Bq * ENCC)     // 25088*1024  (~103 MB)

__device__ __forceinline__ float sigm(float x) { return 1.0f / (1.0f + expf(-x)); }

// ---------------- sort + small outputs (1 block, 128 threads) ----------------
__global__ void k_sort(const int* __restrict__ caplens, const int* __restrict__ captions,
                       float* __restrict__ out, int* __restrict__ sort_ind,
                       int* __restrict__ dec_len, int* __restrict__ caps_ws)
{
    __shared__ int lens[Bq];
    __shared__ int sind[Bq];
    const int b = threadIdx.x;
    lens[b] = caplens[b];
    __syncthreads();
    const int myl = lens[b];
    int rank = 0;
    for (int j = 0; j < Bq; ++j) {
        int lj = lens[j];
        rank += (lj > myl) || (lj == myl && j < b);  // stable descending
    }
    sind[rank] = b;
    __syncthreads();
    const int src = sind[b];
    const int dl = lens[src] - 1;
    sort_ind[b] = src;
    dec_len[b]  = dl;
    out[O_DECL + b] = (float)dl;
    out[O_SORT + b] = (float)src;
    for (int t = 0; t < CAPq; ++t) {
        int cv = captions[src * CAPq + t];
        caps_ws[b * CAPq + t] = cv;
        out[O_CAPS + b * CAPq + t] = (float)cv;
    }
    const float dlf = (float)dl;
    for (int t = 0; t < TMx; ++t)
        out[O_RELP + b * TMx + t] = (t < dl) ? ((float)(t + 1)) / dlf : 0.0f;
}

// ---------------- zero h1,c1,h2,c2 (contiguous 4*128*1024 floats) ----------------
__global__ void k_zero(float* __restrict__ p)
{
    int i = blockIdx.x * 256 + threadIdx.x;
    p[i] = 0.0f;
}

// ---------------- mean_enc ----------------
__global__ void k_mean(const float* __restrict__ enc, const int* __restrict__ si,
                       float* __restrict__ mean_enc)
{
    const int b = blockIdx.y;
    const int e = blockIdx.x * 256 + threadIdx.x;
    const float* p0 = enc + ((size_t)si[b] * Pp) * ENCC + e;
    float s = 0.0f;
    for (int p = 0; p < Pp; ++p) s += p0[(size_t)p * ENCC];
    mean_enc[b * ENCC + e] = s * (1.0f / (float)Pp);
}

// ---------------- generic tiled fp32 GEMM, M=128 rows ----------------
// out(m,n) = sum_k X1[m,k]W1[n,k] (+ X2[m,k]W2[n,k]) (+b1[n]) (+b2[n])
// EPI 0: store to out[m*N+n]
// EPI 1: gate: x2[m*3072+n] = sigmoid(v)*awe[m*2048+n]
// EPI 2: preds: out[(m*21+t)*32000+n] = (t<dec_len[m]) ? v : 0
#define BM 64
#define BN 64
#define BK 16

template<int EPI>
__global__ __launch_bounds__(256)
void gemm_m128(const float* __restrict__ X1, const float* __restrict__ W1, int K1,
               const float* __restrict__ X2, const float* __restrict__ W2, int K2,
               const float* __restrict__ b1, const float* __restrict__ b2,
               float* __restrict__ out, int N,
               const float* __restrict__ awe, const int* __restrict__ dec_len, int t)
{
    __shared__ float Xs[BK][BM + 4];
    __shared__ float Wsh[BK][BN + 4];
    const int tid = threadIdx.x;
    const int tx = tid & 15, ty = tid >> 4;
    const int m0 = blockIdx.y * BM;
    const int n0 = blockIdx.x * BN;
    const int lr = tid >> 2;          // 0..63 : row being staged
    const int lk = (tid & 3) << 2;    // 0,4,8,12 : k-quad

    float acc[4][4] = {};

    for (int pass = 0; pass < 2; ++pass) {
        const float* __restrict__ X = pass ? X2 : X1;
        const float* __restrict__ W = pass ? W2 : W1;
        const int K = pass ? K2 : K1;
        if (X == nullptr) continue;
        const float* Xrow = X + (size_t)(m0 + lr) * K;
        const float* Wrow = W + (size_t)(n0 + lr) * K;
        for (int k0 = 0; k0 < K; k0 += BK) {
            float4 xv = *(const float4*)(Xrow + k0 + lk);
            float4 wv = *(const float4*)(Wrow + k0 + lk);
            __syncthreads();
            Xs[lk + 0][lr] = xv.x; Xs[lk + 1][lr] = xv.y;
            Xs[lk + 2][lr] = xv.z; Xs[lk + 3][lr] = xv.w;
            Wsh[lk + 0][lr] = wv.x; Wsh[lk + 1][lr] = wv.y;
            Wsh[lk + 2][lr] = wv.z; Wsh[lk + 3][lr] = wv.w;
            __syncthreads();
            #pragma unroll
            for (int k = 0; k < BK; ++k) {
                float4 a = *(const float4*)&Xs[k][ty << 2];
                float4 w = *(const float4*)&Wsh[k][tx << 2];
                acc[0][0] += a.x * w.x; acc[0][1] += a.x * w.y; acc[0][2] += a.x * w.z; acc[0][3] += a.x * w.w;
                acc[1][0] += a.y * w.x; acc[1][1] += a.y * w.y; acc[1][2] += a.y * w.z; acc[1][3] += a.y * w.w;
                acc[2][0] += a.z * w.x; acc[2][1] += a.z * w.y; acc[2][2] += a.z * w.z; acc[2][3] += a.z * w.w;
                acc[3][0] += a.w * w.x; acc[3][1] += a.w * w.y; acc[3][2] += a.w * w.z; acc[3][3] += a.w * w.w;
            }
        }
    }

    const int mb = m0 + (ty << 2);
    const int nb = n0 + (tx << 2);
    #pragma unroll
    for (int i = 0; i < 4; ++i) {
        const int m = mb + i;
        float4 v;
        float* vp = &v.x;
        #pragma unroll
        for (int j = 0; j < 4; ++j) {
            float val = acc[i][j];
            const int n = nb + j;
            if (b1) val += b1[n];
            if (b2) val += b2[n];
            if (EPI == 1) {
                val = sigm(val) * awe[m * ENCC + n];
            } else if (EPI == 2) {
                if (t >= dec_len[m]) val = 0.0f;
            }
            vp[j] = val;
        }
        if (EPI == 0)      *(float4*)(out + (size_t)m * N + nb) = v;
        else if (EPI == 1) *(float4*)(out + (size_t)m * (ENCC + Dd) + nb) = v;
        else               *(float4*)(out + ((size_t)m * TMx + t) * Vv + nb) = v;
    }
}

// ---------------- att1 = enc_sorted @ enc_att_W.T + b : M=25088, N=1024, K=2048 ----------------
__global__ __launch_bounds__(256)
void gemm_att1(const float* __restrict__ enc, const float* __restrict__ W,
               const float* __restrict__ bias, const int* __restrict__ si,
               float* __restrict__ out)
{
    __shared__ float Xs[BK][BM + 4];
    __shared__ float Wsh[BK][BN + 4];
    const int tid = threadIdx.x;
    const int tx = tid & 15, ty = tid >> 4;
    const int m0 = blockIdx.y * BM;
    const int n0 = blockIdx.x * BN;
    const int lr = tid >> 2;
    const int lk = (tid & 3) << 2;
    const int m = m0 + lr;
    const int bb = m / Pp;
    const int pp = m - bb * Pp;
    const float* Xrow = enc + ((size_t)si[bb] * Pp + pp) * ENCC;
    const float* Wrow = W + (size_t)(n0 + lr) * ENCC;

    float acc[4][4] = {};
    for (int k0 = 0; k0 < ENCC; k0 += BK) {
        float4 xv = *(const float4*)(Xrow + k0 + lk);
        float4 wv = *(const float4*)(Wrow + k0 + lk);
        __syncthreads();
        Xs[lk + 0][lr] = xv.x; Xs[lk + 1][lr] = xv.y;
        Xs[lk + 2][lr] = xv.z; Xs[lk + 3][lr] = xv.w;
        Wsh[lk + 0][lr] = wv.x; Wsh[lk + 1][lr] = wv.y;
        Wsh[lk + 2][lr] = wv.z; Wsh[lk + 3][lr] = wv.w;
        __syncthreads();
        #pragma unroll
        for (int k = 0; k < BK; ++k) {
            float4 a = *(const float4*)&Xs[k][ty << 2];
            float4 w = *(const float4*)&Wsh[k][tx << 2];
            acc[0][0] += a.x * w.x; acc[0][1] += a.x * w.y; acc[0][2] += a.x * w.z; acc[0][3] += a.x * w.w;
            acc[1][0] += a.y * w.x; acc[1][1] += a.y * w.y; acc[1][2] += a.y * w.z; acc[1][3] += a.y * w.w;
            acc[2][0] += a.z * w.x; acc[2][1] += a.z * w.y; acc[2][2] += a.z * w.z; acc[2][3] += a.z * w.w;
            acc[3][0] += a.w * w.x; acc[3][1] += a.w * w.y; acc[3][2] += a.w * w.z; acc[3][3] += a.w * w.w;
        }
    }
    const int mb = m0 + (ty << 2);
    const int nb = n0 + (tx << 2);
    #pragma unroll
    for (int i = 0; i < 4; ++i) {
        float4 v;
        v.x = acc[i][0] + bias[nb + 0];
        v.y = acc[i][1] + bias[nb + 1];
        v.z = acc[i][2] + bias[nb + 2];
        v.w = acc[i][3] + bias[nb + 3];
        *(float4*)(out + (size_t)(mb + i) * Aa + nb) = v;
    }
}

// ---------------- build x1 = [e_t, h2, mean_enc] ----------------
__global__ void k_x1(const float* __restrict__ emb, const int* __restrict__ caps_ws,
                     const float* __restrict__ h2, const float* __restrict__ mean_enc,
                     float* __restrict__ x1, int t)
{
    const int idx = blockIdx.x * 256 + threadIdx.x;   // < 128*4096
    const int b = idx >> 12;
    const int j = idx & 4095;
    float v;
    if (j < Dd)            v = emb[(size_t)caps_ws[b * CAPq + t] * Dd + j];
    else if (j < 2 * Dd)   v = h2[b * Dd + (j - Dd)];
    else                   v = mean_enc[b * ENCC + (j - 2 * Dd)];
    x1[idx] = v;
}

// ---------------- LSTM pointwise cell (in-place h,c update) ----------------
__global__ void k_cell(const float* __restrict__ g, float* __restrict__ h,
                       float* __restrict__ c, float* __restrict__ x2copy)
{
    const int idx = blockIdx.x * 256 + threadIdx.x;   // < 128*1024
    const int b = idx >> 10;
    const int j = idx & 1023;
    const float* gr = g + (size_t)b * 4096;
    const float gi = gr[j], gf = gr[j + 1024], gg = gr[j + 2048], go = gr[j + 3072];
    const float cv = c[idx];
    const float c2 = sigm(gf) * cv + sigm(gi) * tanhf(gg);
    const float h2 = sigm(go) * tanhf(c2);
    c[idx] = c2;
    h[idx] = h2;
    if (x2copy) x2copy[b * 3072 + 2048 + j] = h2;
}

// ---------------- fused scores -> softmax -> awe (one block per batch row) ----------------
__global__ __launch_bounds__(256)
void k_scores_awe(const float* __restrict__ att1, const float* __restrict__ att2,
                  const float* __restrict__ wfull, const float* __restrict__ bfull,
                  const float* __restrict__ enc, const int* __restrict__ si,
                  float* __restrict__ awe)
{
    __shared__ float a2[Aa];
    __shared__ float wf[Aa];
    __shared__ float sc[Pp];
    __shared__ float red[256];
    const int tid = threadIdx.x;
    const int b = blockIdx.x;
    for (int j = tid; j < Aa; j += 256) { a2[j] = att2[b * Aa + j]; wf[j] = wfull[j]; }
    __syncthreads();
    const int wave = tid >> 6, lane = tid & 63;
    const float fb = bfull[0];
    for (int p = wave; p < Pp; p += 4) {
        const float* row = att1 + ((size_t)b * Pp + p) * Aa;
        float s = 0.0f;
        for (int k = lane; k < Aa; k += 64) s += tanhf(row[k] + a2[k]) * wf[k];
        for (int off = 32; off; off >>= 1) s += __shfl_down(s, off);
        if (lane == 0) sc[p] = s + fb;
    }
    __syncthreads();
    // softmax over p
    float mx = -1e30f;
    for (int p = tid; p < Pp; p += 256) mx = fmaxf(mx, sc[p]);
    red[tid] = mx; __syncthreads();
    for (int s = 128; s > 0; s >>= 1) { if (tid < s) red[tid] = fmaxf(red[tid], red[tid + s]); __syncthreads(); }
    const float m = red[0];
    __syncthreads();
    float sum = 0.0f;
    for (int p = tid; p < Pp; p += 256) { float e = expf(sc[p] - m); sc[p] = e; sum += e; }
    red[tid] = sum; __syncthreads();
    for (int s = 128; s > 0; s >>= 1) { if (tid < s) red[tid] += red[tid + s]; __syncthreads(); }
    const float rden = 1.0f / red[0];
    __syncthreads();
    for (int p = tid; p < Pp; p += 256) sc[p] *= rden;
    __syncthreads();
    // awe[b,e] = sum_p alpha[p]*enc[b,p,e]
    const float* encb = enc + (size_t)si[b] * Pp * ENCC;
    for (int e = tid; e < ENCC; e += 256) {
        float acc = 0.0f;
        #pragma unroll 4
        for (int p = 0; p < Pp; ++p) acc += sc[p] * encb[(size_t)p * ENCC + e];
        awe[b * ENCC + e] = acc;
    }
}

// ---------------- rpm head: predicted_pos ----------------
__global__ void k_rpm(const float* __restrict__ h2, const float* __restrict__ rpm_W,
                      const int* __restrict__ dec_len, float* __restrict__ out, int t)
{
    const int b = blockIdx.x;
    const int lane = threadIdx.x;
    float s = 0.0f;
    for (int k = lane; k < Dd; k += 64) s += h2[b * Dd + k] * rpm_W[k];
    for (int off = 32; off; off >>= 1) s += __shfl_down(s, off);
    if (lane == 0) {
        float r = sigm(s);
        out[O_PPOS + b * TMx + t] = (t < dec_len[b]) ? r : 0.0f;
    }
}

extern "C" void kernel_launch(void* const* d_in, const int* in_sizes, int n_in,
                              void* d_out, int out_size, void* d_ws, size_t ws_size,
                              hipStream_t stream)
{
    const float* encoder_out = (const float*)d_in[0];
    const int*   captions    = (const int*)d_in[1];
    const int*   caplens     = (const int*)d_in[2];
    const float* emb         = (const float*)d_in[3];
    const float* enc_att_W   = (const float*)d_in[4];
    const float* enc_att_b   = (const float*)d_in[5];
    const float* dec_att_W   = (const float*)d_in[6];
    const float* dec_att_b   = (const float*)d_in[7];
    const float* full_att_W  = (const float*)d_in[8];
    const float* full_att_b  = (const float*)d_in[9];
    const float* f_beta_W    = (const float*)d_in[10];
    const float* f_beta_b    = (const float*)d_in[11];
    const float* l1_Wih      = (const float*)d_in[12];
    const float* l1_Whh      = (const float*)d_in[13];
    const float* l1_bih      = (const float*)d_in[14];
    const float* l1_bhh      = (const float*)d_in[15];
    const float* l2_Wih      = (const float*)d_in[16];
    const float* l2_Whh      = (const float*)d_in[17];
    const float* l2_bih      = (const float*)d_in[18];
    const float* l2_bhh      = (const float*)d_in[19];
    const float* ram_W       = (const float*)d_in[20];
    const float* ram_b       = (const float*)d_in[21];
    const float* rpm_W       = (const float*)d_in[22];

    float* ws  = (float*)d_ws;
    float* out = (float*)d_out;
    int* sort_ind = (int*)(ws + WS_SORT);
    int* dec_len  = (int*)(ws + WS_DECL);
    int* caps_ws  = (int*)(ws + WS_CAPS);
    float* h1   = ws + WS_H1;
    float* c1   = ws + WS_C1;
    float* h2   = ws + WS_H2;
    float* c2   = ws + WS_C2;
    float* mean = ws + WS_MEAN;
    float* att2 = ws + WS_ATT2;
    float* x1   = ws + WS_X1;
    float* x2   = ws + WS_X2;
    float* g    = ws + WS_G;
    float* awe  = ws + WS_AWE;
    float* att1 = ws + WS_ATT1;

    // setup
    k_sort<<<1, 128, 0, stream>>>(caplens, captions, out, sort_ind, dec_len, caps_ws);
    k_zero<<<(4 * Bq * Dd) / 256, 256, 0, stream>>>(h1);   // zeroes h1,c1,h2,c2 (contiguous)
    k_mean<<<dim3(ENCC / 256, Bq), 256, 0, stream>>>(encoder_out, sort_ind, mean);
    gemm_att1<<<dim3(Aa / BN, (Bq * Pp) / BM), 256, 0, stream>>>(encoder_out, enc_att_W, enc_att_b, sort_ind, att1);

    for (int t = 0; t < TMx; ++t) {
        k_x1<<<(Bq * 4096) / 256, 256, 0, stream>>>(emb, caps_ws, h2, mean, x1, t);
        // g = x1@W1ih.T + h1@W1hh.T + b1ih + b1hh
        gemm_m128<0><<<dim3(4096 / BN, Bq / BM), 256, 0, stream>>>(
            x1, l1_Wih, 4096, h1, l1_Whh, Dd, l1_bih, l1_bhh, g, 4096, nullptr, nullptr, 0);
        k_cell<<<(Bq * Dd) / 256, 256, 0, stream>>>(g, h1, c1, x2);  // also writes x2[:,2048:]
        // att2 = h1@dec_att_W.T + b
        gemm_m128<0><<<dim3(Aa / BN, Bq / BM), 256, 0, stream>>>(
            h1, dec_att_W, Dd, nullptr, nullptr, 0, dec_att_b, nullptr, att2, Aa, nullptr, nullptr, 0);
        k_scores_awe<<<Bq, 256, 0, stream>>>(att1, att2, full_att_W, full_att_b, encoder_out, sort_ind, awe);
        // x2[:, :2048] = sigmoid(h1@f_beta_W.T + b) * awe
        gemm_m128<1><<<dim3(ENCC / BN, Bq / BM), 256, 0, stream>>>(
            h1, f_beta_W, Dd, nullptr, nullptr, 0, f_beta_b, nullptr, x2, ENCC, awe, nullptr, 0);
        // g = x2@W2ih.T + h2@W2hh.T + b2ih + b2hh
        gemm_m128<0><<<dim3(4096 / BN, Bq / BM), 256, 0, stream>>>(
            x2, l2_Wih, 3072, h2, l2_Whh, Dd, l2_bih, l2_bhh, g, 4096, nullptr, nullptr, 0);
        k_cell<<<(Bq * Dd) / 256, 256, 0, stream>>>(g, h2, c2, nullptr);
        // predictions[:, t, :] = mask ? h2@ram_W.T + ram_b : 0
        gemm_m128<2><<<dim3(Vv / BN, Bq / BM), 256, 0, stream>>>(
            h2, ram_W, Dd, nullptr, nullptr, 0, ram_b, nullptr, out, Vv, nullptr, dec_len, t);
        k_rpm<<<Bq, 64, 0, stream>>>(h2, rpm_W, dec_len, out, t);
    }
}